// Round 14
// baseline (600.013 us; speedup 1.0000x reference)
//
#include <hip/hip_runtime.h>
#include <math.h>

#define B_DIM 1024
#define D_DIM 512
#define H_DIM 128
#define S_DIM 511
#define PI_F 3.14159265358979323846f
#define ZSWZ_BYTES (8u * 1024u * 128u)      /* 1 MiB: z bf16, fragment-ordered */
#define NTILES_TOTAL 2296                    /* sum over s of ceil((s+1)/64) */
#define W1BF_BYTES ((size_t)NTILES_TOTAL * 16384)
#define EPI_OFF 32768                        /* after 2x16KB B slots; epi = 8KB */
#define NCH 128                              /* chains */

typedef __attribute__((ext_vector_type(8))) short short8;
typedef __attribute__((ext_vector_type(4))) float f32x4;

#define GLDS16(src, dst)                                                        \
    __builtin_amdgcn_global_load_lds(                                           \
        (const __attribute__((address_space(1))) unsigned int*)(src),           \
        (__attribute__((address_space(3))) unsigned int*)(dst), 16, 0, 0)

#define SB0() __builtin_amdgcn_sched_barrier(0)

static __device__ __forceinline__ unsigned cvt_pk_bf16(float lo, float hi) {
    unsigned r;
    asm("v_cvt_pk_bf16_f32 %0, %1, %2" : "=v"(r) : "v"(lo), "v"(hi));
    return r;
}

// 64-wide k-tiles before site s in the packed W1bf buffer
static __device__ __forceinline__ int tiles_before(int s) {
    const int q = s >> 6, r = s & 63;
    return s + 32 * q * (q - 1) + q * r;
}

// Fragment-ordered 16KB tile (128 rows x 64 k bf16), verified R9/R10/R13:
//   chunk(row r, k-granule g 0..7) at ((r>>4)*2+(g>>2))*1024 + (g&3)*256 + (r&15)*16

// ---------------------------------------------------------------------------
// Pack kernel (verified R9-R13). z -> frag-ordered bf16 tiles [rb128][kt];
// W1 -> frag-ordered [h][k] 16KB tiles, triangular-packed, K-mask baked in.
// ---------------------------------------------------------------------------
__global__ __launch_bounds__(256) void pack_kernel(
        const float* __restrict__ z, const float* __restrict__ W1,
        unsigned char* __restrict__ z_frag, unsigned char* __restrict__ w1bf)
{
    if (blockIdx.x < 256) {
        const int gid = blockIdx.x * 256 + threadIdx.x;   // 65536 threads
        const int g   = gid & 7;
        const int row = (gid >> 3) & 1023;
        const int kt  = gid >> 13;
        const float* src = z + (size_t)row * D_DIM + kt * 64 + g * 8;
        float4 a = *(const float4*)src;
        float4 b = *(const float4*)(src + 4);
        uint4 w;
        w.x = cvt_pk_bf16(a.x, a.y);
        w.y = cvt_pk_bf16(a.z, a.w);
        w.z = cvt_pk_bf16(b.x, b.y);
        w.w = cvt_pk_bf16(b.z, b.w);
        const int r7 = row & 127;
        const int tile = (row >> 7) * 8 + kt;
        const int off = (((r7 >> 4) * 2 + (g >> 2)) << 10) + ((g & 3) << 8) + ((r7 & 15) << 4);
        *(uint4*)(z_frag + (size_t)tile * 16384 + off) = w;
        return;
    }
    const int tb = blockIdx.x - 256;          // 0..4087
    const int s  = tb >> 3;
    const int kk = tb & 7;
    if (s >= S_DIM || kk > (s >> 6)) return;
    const int k0 = kk << 6;
    const int t  = threadIdx.x;
    const int h2 = t & 63;
    const int mw = t >> 6;
    const float* __restrict__ W1s = W1 + (size_t)s * (D_DIM * H_DIM);
    unsigned char* out = w1bf + (size_t)(tiles_before(s) + kk) * 16384;
    const int h0 = h2 * 2, h1 = h2 * 2 + 1;
#pragma unroll
    for (int half = 0; half < 2; ++half) {
        const int m = mw + half * 4;
        float2 v[8];
#pragma unroll
        for (int e = 0; e < 8; ++e) {
            const int gk = k0 + m * 8 + e;
            v[e] = (gk <= s) ? *(const float2*)(W1s + (size_t)gk * H_DIM + h0)
                             : (float2){0.f, 0.f};
        }
        uint4 w0, w1;
        w0.x = cvt_pk_bf16(v[0].x, v[1].x); w0.y = cvt_pk_bf16(v[2].x, v[3].x);
        w0.z = cvt_pk_bf16(v[4].x, v[5].x); w0.w = cvt_pk_bf16(v[6].x, v[7].x);
        w1.x = cvt_pk_bf16(v[0].y, v[1].y); w1.y = cvt_pk_bf16(v[2].y, v[3].y);
        w1.z = cvt_pk_bf16(v[4].y, v[5].y); w1.w = cvt_pk_bf16(v[6].y, v[7].y);
        const int base0 = (((h0 >> 4) * 2 + (m >> 2)) << 10) + ((m & 3) << 8);
        *(uint4*)(out + base0 + ((h0 & 15) << 4)) = w0;
        *(uint4*)(out + base0 + ((h1 & 15) << 4)) = w1;
    }
}

// ---------------------------------------------------------------------------
// Dual-pipe chained kernel, 4 barrier domains/CU (PRE=true):
// 1024 blocks x 256 thr, tile 128x128, 4 waves (2x2, 64x64 each), LDS 40KB
// -> 4 blocks/CU, 4 waves/SIMD. A (z frags): L2 -> registers, dbuf.
// B (W1 tile): glds -> 16KB LDS slot (4 glds/wave). One barrier + counted
// vmcnt(8) per step; SB0 pins VMEM order [B(k+1) x4, A(k+2) x8].
// Cross-BLOCK slip (independent barrier domains) hides per-domain stalls.
// ---------------------------------------------------------------------------
template<bool PRE>
__global__ __launch_bounds__(256, 4) void ar_site_kernel(
        const float* __restrict__ z, const unsigned char* __restrict__ z_frag,
        const unsigned char* __restrict__ w1bf,
        const float* __restrict__ W1, const float* __restrict__ b1,
        const float* __restrict__ W2, const float* __restrict__ b2,
        float* __restrict__ x_out, float* __restrict__ ld_out)
{
    __shared__ __align__(16) unsigned char lds[40960]; // 2x16KB B slots + 8KB epi

    const int tid  = threadIdx.x;
    const int lane = tid & 63;
    const int wid  = tid >> 6;
    const int l15  = lane & 15;
    const int l16  = lane >> 4;

    if (PRE) {
        const int wr   = wid >> 1;              // 0..1: rows wr*64..+63
        const int wc   = wid & 1;               // 0..1: cols wc*64..+63
        const int ib   = blockIdx.x;            // 0..1023
        const int c    = ib & (NCH - 1);        // chain 0..127 (XCD = c&7)
        const int bblk = ib >> 7;               // 0..7 (128-row block)
        const int brow0 = bblk * 128;
        const int abase = ((wr * 8) << 10) + lane * 16;

        // independent prefetch cursors: A (2 steps ahead), B (1 step ahead)
        int pfA_t = 0, pfA_kk = 0, pfA_s = 510 - c;
        int pfB_t = 0, pfB_kk = 0, pfB_s = 510 - c;
        int pfB_base = tiles_before(pfB_s);

#define ADV(T, KK, S, HASB)                                                     \
        ++KK;                                                                   \
        if (KK == ((S >> 6) + 1)) {                                             \
            KK = 0; ++T;                                                        \
            while (T < 4) {                                                     \
                const int jj = T * NCH + ((T & 1) ? (NCH - 1 - c) : c);         \
                if (jj < S_DIM) { S = 510 - jj; if (HASB) pfB_base = tiles_before(S); break; } \
                ++T;                                                            \
            }                                                                   \
        }

#define ISSUE_A(BUF)                                                            \
        if (pfA_t < 4) {                                                        \
            const unsigned char* srcA = z_frag                                  \
                + (((size_t)(bblk * 8 + pfA_kk)) << 14) + abase;                \
            _Pragma("unroll")                                                   \
            for (int i = 0; i < 8; ++i)                                         \
                BUF[i] = *(const short8*)(srcA + (i << 10));                    \
            ADV(pfA_t, pfA_kk, pfA_s, 0)                                        \
        }

#define ISSUE_B(SL)                                                             \
        if (pfB_t < 4) {                                                        \
            const unsigned char* srcB = w1bf                                    \
                + (((size_t)(pfB_base + pfB_kk)) << 14) + wid * 4096 + lane * 16;\
            unsigned char* dstB = lds + (SL) * 16384 + wid * 4096;              \
            GLDS16(srcB, dstB);                                                 \
            GLDS16(srcB + 1024, dstB + 1024);                                   \
            GLDS16(srcB + 2048, dstB + 2048);                                   \
            GLDS16(srcB + 3072, dstB + 3072);                                   \
            ADV(pfB_t, pfB_kk, pfB_s, 1)                                        \
        }

#define BODY(CUR)                                                               \
        {                                                                       \
            if (step + 1 == csteps) { asm volatile("s_waitcnt vmcnt(0)" ::: "memory"); } \
            else                    { asm volatile("s_waitcnt vmcnt(8)" ::: "memory"); } \
            __builtin_amdgcn_s_barrier();                                       \
            SB0();                                                              \
            const int sl = step & 1;                                            \
            ISSUE_B(sl ^ 1)                                                     \
            SB0();   /* pin: B glds issued before everything below */           \
            short8 BF[8];                                                       \
            _Pragma("unroll")                                                   \
            for (int i = 0; i < 8; ++i)                                         \
                BF[i] = *(const short8*)(lds + sl * 16384                       \
                         + (((wc * 4 + (i >> 1)) * 2 + (i & 1)) << 10)          \
                         + l16 * 256 + l15 * 16);                               \
            __builtin_amdgcn_s_setprio(1);                                      \
            _Pragma("unroll")                                                   \
            for (int ks = 0; ks < 2; ++ks)                                      \
                _Pragma("unroll")                                               \
                for (int mi = 0; mi < 4; ++mi)                                  \
                    _Pragma("unroll")                                           \
                    for (int ni = 0; ni < 4; ++ni)                              \
                        acc[mi][ni] = __builtin_amdgcn_mfma_f32_16x16x32_bf16(  \
                            CUR[mi * 2 + ks], BF[ni * 2 + ks], acc[mi][ni], 0, 0, 0); \
            __builtin_amdgcn_s_setprio(0);                                      \
            SB0();   /* pin: A loads issued after MFMA, after B glds */         \
            ISSUE_A(CUR)                                                        \
            SB0();                                                              \
            ++step;                                                             \
        }

        int csteps = 0;
#pragma unroll
        for (int t = 0; t < 4; ++t) {
            const int j = t * NCH + ((t & 1) ? (NCH - 1 - c) : c);
            if (j < S_DIM) csteps += ((510 - j) >> 6) + 1;
        }

        short8 A0[8], A1[8];
        ISSUE_A(A0)                 // A(0)
        SB0();
        ISSUE_B(0)                  // B(0) -> slot 0
        SB0();
        ISSUE_A(A1)                 // A(1)   queue: [A0 x8, B0 x4, A1 x8]
        SB0();

        int step = 0;
        bool par = false;
        float ld_acc = 0.f;

        for (int t = 0; t < 4; ++t) {
            const int j = t * NCH + ((t & 1) ? (NCH - 1 - c) : c);
            if (j >= S_DIM) continue;
            const int s   = 510 - j;
            const int nt  = (s >> 6) + 1;
            const int idx = s + 1;

            f32x4 acc[4][4];
#pragma unroll
            for (int mi = 0; mi < 4; ++mi)
#pragma unroll
                for (int ni = 0; ni < 4; ++ni)
                    acc[mi][ni] = (f32x4){0.f, 0.f, 0.f, 0.f};

            for (int kk = 0; kk < nt; ++kk) {
                if (!par) BODY(A0) else BODY(A1)
                par = !par;
            }
            SB0();

            // ---- site epilogue: p = relu(acc+b1) @ W2, then NCP transform
            float b1v[4], w2a[4], w2b[4];
#pragma unroll
            for (int ni = 0; ni < 4; ++ni) {
                const int cc = wc * 64 + ni * 16 + l15;
                b1v[ni] = b1[(size_t)s * H_DIM + cc];
                const float2 w2v = *(const float2*)(W2 + ((size_t)s * H_DIM + cc) * 2);
                w2a[ni] = w2v.x;
                w2b[ni] = w2v.y;
            }
            float p0s[4][4], p1s[4][4];
#pragma unroll
            for (int mi = 0; mi < 4; ++mi)
#pragma unroll
                for (int r = 0; r < 4; ++r) {
                    float p0 = 0.f, p1 = 0.f;
#pragma unroll
                    for (int ni = 0; ni < 4; ++ni) {
                        float h = fmaxf(acc[mi][ni][r] + b1v[ni], 0.f);
                        p0 = fmaf(h, w2a[ni], p0);
                        p1 = fmaf(h, w2b[ni], p1);
                    }
                    p0s[mi][r] = p0; p1s[mi][r] = p1;
                }
#pragma unroll
            for (int mi = 0; mi < 4; ++mi)
#pragma unroll
                for (int r = 0; r < 4; ++r) {
                    p0s[mi][r] += __shfl_xor(p0s[mi][r], 1);
                    p0s[mi][r] += __shfl_xor(p0s[mi][r], 2);
                    p1s[mi][r] += __shfl_xor(p1s[mi][r], 1);
                    p1s[mi][r] += __shfl_xor(p1s[mi][r], 2);
                }
            if ((lane & 3) == 0) {
                const int cw = wc * 4 + (l15 >> 2);
#pragma unroll
                for (int mi = 0; mi < 4; ++mi)
#pragma unroll
                    for (int r = 0; r < 4; ++r) {
                        const int row = wr * 64 + mi * 16 + l16 * 4 + r;   // 0..127
                        *(float2*)(lds + EPI_OFF + (row * 8 + (cw ^ (row & 7))) * 8)
                            = (float2){p0s[mi][r], p1s[mi][r]};
                    }
            }
            asm volatile("s_waitcnt lgkmcnt(0)" ::: "memory");
            __builtin_amdgcn_s_barrier();
            SB0();
            {
                const int row  = tid >> 1;     // 0..127, all 256 threads work
                const int half = tid & 1;
                float a0 = 0.f, b0 = 0.f;
#pragma unroll
                for (int q = 0; q < 4; ++q) {
                    const int cw = half * 4 + q;
                    const float2 v = *(const float2*)(lds + EPI_OFF
                                        + (row * 8 + (cw ^ (row & 7))) * 8);
                    a0 += v.x; b0 += v.y;
                }
                a0 += __shfl_xor(a0, 1);
                b0 += __shfl_xor(b0, 1);
                if (half == 0) {
                    const float alpha = a0 + b2[(size_t)s * 2 + 0];
                    const float beta  = b0 + b2[(size_t)s * 2 + 1];
                    const int grow = brow0 + row;
                    const float phi = z[(size_t)grow * D_DIM + idx];
                    const float u = tanf(0.5f * (phi - PI_F));
                    const float a = expf(alpha);
                    const float v = fmaf(a, u, beta);
                    x_out[(size_t)grow * D_DIM + idx] = 2.0f * atanf(v) + PI_F;
                    ld_acc += alpha + log1pf(u * u) - log1pf(v * v);
                }
            }
            __builtin_amdgcn_s_barrier();     // epi region reusable next site
        }
        if ((tid & 1) == 0) atomicAdd(ld_out + brow0 + (tid >> 1), ld_acc);
        if (c == 0 && tid < 128)
            x_out[(size_t)(brow0 + tid) * D_DIM] = z[(size_t)(brow0 + tid) * D_DIM];
        return;
#undef BODY
#undef ISSUE_A
#undef ISSUE_B
#undef ADV
    }

    // ---------------- legacy fallback: one site per block, in-kernel cvt ----
    const int wr2 = wid >> 1, wc2 = wid & 1;
    const int EPI2 = 32768;
    const int ib    = blockIdx.x;
    const int s_idx = ((ib >> 6) << 3) | (ib & 7);
    if (s_idx >= S_DIM) return;
    const int s     = S_DIM - 1 - s_idx;
    const int bblk  = (ib >> 3) & 7;
    const int brow0 = bblk * 128;
    const int K     = s + 1;
    const int idx   = s + 1;
    const float* __restrict__ W1s = W1 + (size_t)s * (D_DIM * H_DIM);

    f32x4 acc[4][4];
#pragma unroll
    for (int mi = 0; mi < 4; ++mi)
#pragma unroll
        for (int ni = 0; ni < 4; ++ni)
            acc[mi][ni] = (f32x4){0.f, 0.f, 0.f, 0.f};

    const int ntiles = (K + 63) >> 6;
    for (int kk = 0; kk < ntiles; ++kk) {
        const int k0 = kk << 6;
        const int g  = tid & 7;
        const int rb = tid >> 3;
#pragma unroll
        for (int p = 0; p < 4; ++p) {
            const int row  = p * 32 + rb;
            const int srcg = g ^ (row & 7);
            const float* zp = z + (size_t)(brow0 + row) * D_DIM + k0 + srcg * 8;
            float4 va = *(const float4*)zp;
            float4 vb = *(const float4*)(zp + 4);
            uint4 w;
            w.x = cvt_pk_bf16(va.x, va.y);
            w.y = cvt_pk_bf16(va.z, va.w);
            w.z = cvt_pk_bf16(vb.x, vb.y);
            w.w = cvt_pk_bf16(vb.z, vb.w);
            *(uint4*)(lds + row * 128 + g * 16) = w;
        }
        const int hgrp  = tid & 31;
        const int kgrp  = tid >> 5;
        const int kbase = k0 + kgrp * 8;
        const float* wp = W1s + (size_t)kbase * H_DIM + hgrp * 4;
        float4 cc[8];
#pragma unroll
        for (int jj = 0; jj < 8; ++jj) {
            float4 v = *(const float4*)(wp + (size_t)jj * H_DIM);
            const bool ok = (kbase + jj) < K;
            v.x = ok ? v.x : 0.f;  v.y = ok ? v.y : 0.f;
            v.z = ok ? v.z : 0.f;  v.w = ok ? v.w : 0.f;
            cc[jj] = v;
        }
        const float* cf = (const float*)cc;
#pragma unroll
        for (int i2 = 0; i2 < 4; ++i2) {
            const int h = hgrp * 4 + i2;
            uint4 w;
            w.x = cvt_pk_bf16(cf[0 * 4 + i2], cf[1 * 4 + i2]);
            w.y = cvt_pk_bf16(cf[2 * 4 + i2], cf[3 * 4 + i2]);
            w.z = cvt_pk_bf16(cf[4 * 4 + i2], cf[5 * 4 + i2]);
            w.w = cvt_pk_bf16(cf[6 * 4 + i2], cf[7 * 4 + i2]);
            *(uint4*)(lds + 16384 + h * 128 + ((kgrp * 16) ^ ((h & 7) << 4))) = w;
        }
        __syncthreads();
#pragma unroll
        for (int ks = 0; ks < 2; ++ks) {
            const int kb = ks * 64 + l16 * 16;
            short8 af[4], bfr[4];
#pragma unroll
            for (int mi = 0; mi < 4; ++mi) {
                const int r = wr2 * 64 + mi * 16 + l15;
                af[mi] = *(const short8*)(lds + r * 128 + (kb ^ ((r & 7) << 4)));
            }
#pragma unroll
            for (int ni = 0; ni < 4; ++ni) {
                const int h = wc2 * 64 + ni * 16 + l15;
                bfr[ni] = *(const short8*)(lds + 16384 + h * 128 + (kb ^ ((h & 7) << 4)));
            }
#pragma unroll
            for (int mi = 0; mi < 4; ++mi)
#pragma unroll
                for (int ni = 0; ni < 4; ++ni)
                    acc[mi][ni] = __builtin_amdgcn_mfma_f32_16x16x32_bf16(
                        af[mi], bfr[ni], acc[mi][ni], 0, 0, 0);
        }
        __syncthreads();
    }

    float b1v[4], w2a[4], w2b[4];
#pragma unroll
    for (int ni = 0; ni < 4; ++ni) {
        const int cc2 = wc2 * 64 + ni * 16 + l15;
        b1v[ni] = b1[(size_t)s * H_DIM + cc2];
        const float* w2p = W2 + ((size_t)s * H_DIM + cc2) * 2;
        w2a[ni] = w2p[0];
        w2b[ni] = w2p[1];
    }
    float p0s[4][4], p1s[4][4];
#pragma unroll
    for (int mi = 0; mi < 4; ++mi)
#pragma unroll
        for (int r = 0; r < 4; ++r) {
            float p0 = 0.f, p1 = 0.f;
#pragma unroll
            for (int ni = 0; ni < 4; ++ni) {
                float h = fmaxf(acc[mi][ni][r] + b1v[ni], 0.f);
                p0 = fmaf(h, w2a[ni], p0);
                p1 = fmaf(h, w2b[ni], p1);
            }
            p0s[mi][r] = p0; p1s[mi][r] = p1;
        }
#pragma unroll
    for (int mi = 0; mi < 4; ++mi)
#pragma unroll
        for (int r = 0; r < 4; ++r) {
            p0s[mi][r] += __shfl_xor(p0s[mi][r], 1);
            p0s[mi][r] += __shfl_xor(p0s[mi][r], 2);
            p1s[mi][r] += __shfl_xor(p1s[mi][r], 1);
            p1s[mi][r] += __shfl_xor(p1s[mi][r], 2);
        }
    if ((lane & 3) == 0) {
        const int cw = wc2 * 4 + (l15 >> 2);
#pragma unroll
        for (int mi = 0; mi < 4; ++mi)
#pragma unroll
            for (int r = 0; r < 4; ++r) {
                const int row = wr2 * 64 + mi * 16 + l16 * 4 + r;
                *(float2*)(lds + EPI2 + (row * 8 + (cw ^ (row & 7))) * 8)
                    = (float2){p0s[mi][r], p1s[mi][r]};
            }
    }
    __syncthreads();
    if (tid < 128) {
        const int row = tid;
        float alpha = b2[(size_t)s * 2 + 0];
        float beta  = b2[(size_t)s * 2 + 1];
#pragma unroll
        for (int cw = 0; cw < 8; ++cw) {
            const float2 v = *(const float2*)(lds + EPI2 + (row * 8 + (cw ^ (row & 7))) * 8);
            alpha += v.x; beta += v.y;
        }
        const int grow = brow0 + row;
        const float phi = z[(size_t)grow * D_DIM + idx];
        const float u = tanf(0.5f * (phi - PI_F));
        const float a = expf(alpha);
        const float v = fmaf(a, u, beta);
        x_out[(size_t)grow * D_DIM + idx] = 2.0f * atanf(v) + PI_F;
        atomicAdd(ld_out + grow, alpha + log1pf(u * u) - log1pf(v * v));
        if (s_idx == 0)
            x_out[(size_t)grow * D_DIM] = z[(size_t)grow * D_DIM];
    }
}

extern "C" void kernel_launch(void* const* d_in, const int* in_sizes, int n_in,
                              void* d_out, int out_size, void* d_ws, size_t ws_size,
                              hipStream_t stream) {
    const float* z  = (const float*)d_in[0];
    const float* W1 = (const float*)d_in[1];
    const float* b1 = (const float*)d_in[2];
    const float* W2 = (const float*)d_in[3];
    const float* b2 = (const float*)d_in[4];
    float* x_out  = (float*)d_out;
    float* ld_out = x_out + (size_t)B_DIM * D_DIM;

    unsigned char* z_frag = (unsigned char*)d_ws;
    unsigned char* w1bf   = z_frag + ZSWZ_BYTES;
    const size_t need = ZSWZ_BYTES + W1BF_BYTES;

    hipMemsetAsync(ld_out, 0, B_DIM * sizeof(float), stream);
    if (ws_size >= need) {
        pack_kernel<<<dim3(256 + 4088), dim3(256), 0, stream>>>(z, W1, z_frag, w1bf);
        ar_site_kernel<true><<<dim3(1024), dim3(256), 0, stream>>>(
            z, z_frag, w1bf, W1, b1, W2, b2, x_out, ld_out);
    } else {
        ar_site_kernel<false><<<dim3(4096), dim3(256), 0, stream>>>(
            z, nullptr, nullptr, W1, b1, W2, b2, x_out, ld_out);
    }
}

// Round 15
// 112.633 us; speedup vs baseline: 5.3271x; 5.3271x over previous
//
#include <hip/hip_runtime.h>
#include <math.h>

#define B_DIM 1024
#define D_DIM 512
#define H_DIM 128
#define S_DIM 511
#define PI_F 3.14159265358979323846f
#define ZSWZ_BYTES (8u * 1024u * 128u)      /* 1 MiB: z bf16, fragment-ordered */
#define NTILES_TOTAL 2296                    /* sum over s of ceil((s+1)/64) */
#define W1BF_BYTES ((size_t)NTILES_TOTAL * 16384)
#define EPI_OFF 32768                        /* after 2x16KB B slots; epi = 8KB */
#define NCH 128                              /* chains */

typedef __attribute__((ext_vector_type(8))) short short8;
typedef __attribute__((ext_vector_type(4))) float f32x4;

#define GLDS16(src, dst)                                                        \
    __builtin_amdgcn_global_load_lds(                                           \
        (const __attribute__((address_space(1))) unsigned int*)(src),           \
        (__attribute__((address_space(3))) unsigned int*)(dst), 16, 0, 0)

#define SB0() __builtin_amdgcn_sched_barrier(0)

static __device__ __forceinline__ unsigned cvt_pk_bf16(float lo, float hi) {
    unsigned r;
    asm("v_cvt_pk_bf16_f32 %0, %1, %2" : "=v"(r) : "v"(lo), "v"(hi));
    return r;
}

// 64-wide k-tiles before site s in the packed W1bf buffer
static __device__ __forceinline__ int tiles_before(int s) {
    const int q = s >> 6, r = s & 63;
    return s + 32 * q * (q - 1) + q * r;
}

// Fragment-ordered 16KB tile (128 rows x 64 k bf16), verified R9-R14:
//   chunk(row r, k-granule g 0..7) at ((r>>4)*2+(g>>2))*1024 + (g&3)*256 + (r&15)*16

// ---------------------------------------------------------------------------
// Pack kernel (verified R9-R14). z -> frag-ordered bf16 tiles [rb128][kt];
// W1 -> frag-ordered [h][k] 16KB tiles, triangular-packed, K-mask baked in.
// ---------------------------------------------------------------------------
__global__ __launch_bounds__(256) void pack_kernel(
        const float* __restrict__ z, const float* __restrict__ W1,
        unsigned char* __restrict__ z_frag, unsigned char* __restrict__ w1bf)
{
    if (blockIdx.x < 256) {
        const int gid = blockIdx.x * 256 + threadIdx.x;   // 65536 threads
        const int g   = gid & 7;
        const int row = (gid >> 3) & 1023;
        const int kt  = gid >> 13;
        const float* src = z + (size_t)row * D_DIM + kt * 64 + g * 8;
        float4 a = *(const float4*)src;
        float4 b = *(const float4*)(src + 4);
        uint4 w;
        w.x = cvt_pk_bf16(a.x, a.y);
        w.y = cvt_pk_bf16(a.z, a.w);
        w.z = cvt_pk_bf16(b.x, b.y);
        w.w = cvt_pk_bf16(b.z, b.w);
        const int r7 = row & 127;
        const int tile = (row >> 7) * 8 + kt;
        const int off = (((r7 >> 4) * 2 + (g >> 2)) << 10) + ((g & 3) << 8) + ((r7 & 15) << 4);
        *(uint4*)(z_frag + (size_t)tile * 16384 + off) = w;
        return;
    }
    const int tb = blockIdx.x - 256;          // 0..4087
    const int s  = tb >> 3;
    const int kk = tb & 7;
    if (s >= S_DIM || kk > (s >> 6)) return;
    const int k0 = kk << 6;
    const int t  = threadIdx.x;
    const int h2 = t & 63;
    const int mw = t >> 6;
    const float* __restrict__ W1s = W1 + (size_t)s * (D_DIM * H_DIM);
    unsigned char* out = w1bf + (size_t)(tiles_before(s) + kk) * 16384;
    const int h0 = h2 * 2, h1 = h2 * 2 + 1;
#pragma unroll
    for (int half = 0; half < 2; ++half) {
        const int m = mw + half * 4;
        float2 v[8];
#pragma unroll
        for (int e = 0; e < 8; ++e) {
            const int gk = k0 + m * 8 + e;
            v[e] = (gk <= s) ? *(const float2*)(W1s + (size_t)gk * H_DIM + h0)
                             : (float2){0.f, 0.f};
        }
        uint4 w0, w1;
        w0.x = cvt_pk_bf16(v[0].x, v[1].x); w0.y = cvt_pk_bf16(v[2].x, v[3].x);
        w0.z = cvt_pk_bf16(v[4].x, v[5].x); w0.w = cvt_pk_bf16(v[6].x, v[7].x);
        w1.x = cvt_pk_bf16(v[0].y, v[1].y); w1.y = cvt_pk_bf16(v[2].y, v[3].y);
        w1.z = cvt_pk_bf16(v[4].y, v[5].y); w1.w = cvt_pk_bf16(v[6].y, v[7].y);
        const int base0 = (((h0 >> 4) * 2 + (m >> 2)) << 10) + ((m & 3) << 8);
        *(uint4*)(out + base0 + ((h0 & 15) << 4)) = w0;
        *(uint4*)(out + base0 + ((h1 & 15) << 4)) = w1;
    }
}

// ---------------------------------------------------------------------------
// Dual-pipe chained kernel, multi-domain (PRE=true): 1024 blocks x 256 thr,
// tile 128x128, 4 waves (2x2, 64x64 each), LDS 40KB. A: L2 -> regs, dbuf.
// B: glds -> 16KB LDS slot. One barrier + counted vmcnt(8) per step; SB0
// pins VMEM order. R15 FIX vs R14: __launch_bounds__(256,2) — the (256,4)
// bound clamped VGPR to 64 and spilled acc+A-bufs to scratch (1.7GB writes,
// 600us). With the natural ~128-160 VGPR allocation, LDS(40KB) and VGPR
// admit 3-4 blocks/CU = 3-4 independent barrier domains (the R6/R8 lever).
// ---------------------------------------------------------------------------
template<bool PRE>
__global__ __launch_bounds__(256, 2) void ar_site_kernel(
        const float* __restrict__ z, const unsigned char* __restrict__ z_frag,
        const unsigned char* __restrict__ w1bf,
        const float* __restrict__ W1, const float* __restrict__ b1,
        const float* __restrict__ W2, const float* __restrict__ b2,
        float* __restrict__ x_out, float* __restrict__ ld_out)
{
    __shared__ __align__(16) unsigned char lds[40960]; // 2x16KB B slots + 8KB epi

    const int tid  = threadIdx.x;
    const int lane = tid & 63;
    const int wid  = tid >> 6;
    const int l15  = lane & 15;
    const int l16  = lane >> 4;

    if (PRE) {
        const int wr   = wid >> 1;              // 0..1: rows wr*64..+63
        const int wc   = wid & 1;               // 0..1: cols wc*64..+63
        const int ib   = blockIdx.x;            // 0..1023
        const int c    = ib & (NCH - 1);        // chain 0..127 (XCD = c&7)
        const int bblk = ib >> 7;               // 0..7 (128-row block)
        const int brow0 = bblk * 128;
        const int abase = ((wr * 8) << 10) + lane * 16;

        // independent prefetch cursors: A (2 steps ahead), B (1 step ahead)
        int pfA_t = 0, pfA_kk = 0, pfA_s = 510 - c;
        int pfB_t = 0, pfB_kk = 0, pfB_s = 510 - c;
        int pfB_base = tiles_before(pfB_s);

#define ADV(T, KK, S, HASB)                                                     \
        ++KK;                                                                   \
        if (KK == ((S >> 6) + 1)) {                                             \
            KK = 0; ++T;                                                        \
            while (T < 4) {                                                     \
                const int jj = T * NCH + ((T & 1) ? (NCH - 1 - c) : c);         \
                if (jj < S_DIM) { S = 510 - jj; if (HASB) pfB_base = tiles_before(S); break; } \
                ++T;                                                            \
            }                                                                   \
        }

#define ISSUE_A(BUF)                                                            \
        if (pfA_t < 4) {                                                        \
            const unsigned char* srcA = z_frag                                  \
                + (((size_t)(bblk * 8 + pfA_kk)) << 14) + abase;                \
            _Pragma("unroll")                                                   \
            for (int i = 0; i < 8; ++i)                                         \
                BUF[i] = *(const short8*)(srcA + (i << 10));                    \
            ADV(pfA_t, pfA_kk, pfA_s, 0)                                        \
        }

#define ISSUE_B(SL)                                                             \
        if (pfB_t < 4) {                                                        \
            const unsigned char* srcB = w1bf                                    \
                + (((size_t)(pfB_base + pfB_kk)) << 14) + wid * 4096 + lane * 16;\
            unsigned char* dstB = lds + (SL) * 16384 + wid * 4096;              \
            GLDS16(srcB, dstB);                                                 \
            GLDS16(srcB + 1024, dstB + 1024);                                   \
            GLDS16(srcB + 2048, dstB + 2048);                                   \
            GLDS16(srcB + 3072, dstB + 3072);                                   \
            ADV(pfB_t, pfB_kk, pfB_s, 1)                                        \
        }

#define BODY(CUR)                                                               \
        {                                                                       \
            if (step + 1 == csteps) { asm volatile("s_waitcnt vmcnt(0)" ::: "memory"); } \
            else                    { asm volatile("s_waitcnt vmcnt(8)" ::: "memory"); } \
            __builtin_amdgcn_s_barrier();                                       \
            SB0();                                                              \
            const int sl = step & 1;                                            \
            ISSUE_B(sl ^ 1)                                                     \
            SB0();   /* pin: B glds issued before everything below */           \
            short8 BF[8];                                                       \
            _Pragma("unroll")                                                   \
            for (int i = 0; i < 8; ++i)                                         \
                BF[i] = *(const short8*)(lds + sl * 16384                       \
                         + (((wc * 4 + (i >> 1)) * 2 + (i & 1)) << 10)          \
                         + l16 * 256 + l15 * 16);                               \
            __builtin_amdgcn_s_setprio(1);                                      \
            _Pragma("unroll")                                                   \
            for (int ks = 0; ks < 2; ++ks)                                      \
                _Pragma("unroll")                                               \
                for (int mi = 0; mi < 4; ++mi)                                  \
                    _Pragma("unroll")                                           \
                    for (int ni = 0; ni < 4; ++ni)                              \
                        acc[mi][ni] = __builtin_amdgcn_mfma_f32_16x16x32_bf16(  \
                            CUR[mi * 2 + ks], BF[ni * 2 + ks], acc[mi][ni], 0, 0, 0); \
            __builtin_amdgcn_s_setprio(0);                                      \
            SB0();   /* pin: A loads issued after MFMA, after B glds */         \
            ISSUE_A(CUR)                                                        \
            SB0();                                                              \
            ++step;                                                             \
        }

        int csteps = 0;
#pragma unroll
        for (int t = 0; t < 4; ++t) {
            const int j = t * NCH + ((t & 1) ? (NCH - 1 - c) : c);
            if (j < S_DIM) csteps += ((510 - j) >> 6) + 1;
        }

        short8 A0[8], A1[8];
        ISSUE_A(A0)                 // A(0)
        SB0();
        ISSUE_B(0)                  // B(0) -> slot 0
        SB0();
        ISSUE_A(A1)                 // A(1)   queue: [A0 x8, B0 x4, A1 x8]
        SB0();

        int step = 0;
        bool par = false;
        float ld_acc = 0.f;

        for (int t = 0; t < 4; ++t) {
            const int j = t * NCH + ((t & 1) ? (NCH - 1 - c) : c);
            if (j >= S_DIM) continue;
            const int s   = 510 - j;
            const int nt  = (s >> 6) + 1;
            const int idx = s + 1;

            f32x4 acc[4][4];
#pragma unroll
            for (int mi = 0; mi < 4; ++mi)
#pragma unroll
                for (int ni = 0; ni < 4; ++ni)
                    acc[mi][ni] = (f32x4){0.f, 0.f, 0.f, 0.f};

            for (int kk = 0; kk < nt; ++kk) {
                if (!par) BODY(A0) else BODY(A1)
                par = !par;
            }
            SB0();

            // ---- site epilogue: p = relu(acc+b1) @ W2, then NCP transform
            float b1v[4], w2a[4], w2b[4];
#pragma unroll
            for (int ni = 0; ni < 4; ++ni) {
                const int cc = wc * 64 + ni * 16 + l15;
                b1v[ni] = b1[(size_t)s * H_DIM + cc];
                const float2 w2v = *(const float2*)(W2 + ((size_t)s * H_DIM + cc) * 2);
                w2a[ni] = w2v.x;
                w2b[ni] = w2v.y;
            }
            float p0s[4][4], p1s[4][4];
#pragma unroll
            for (int mi = 0; mi < 4; ++mi)
#pragma unroll
                for (int r = 0; r < 4; ++r) {
                    float p0 = 0.f, p1 = 0.f;
#pragma unroll
                    for (int ni = 0; ni < 4; ++ni) {
                        float h = fmaxf(acc[mi][ni][r] + b1v[ni], 0.f);
                        p0 = fmaf(h, w2a[ni], p0);
                        p1 = fmaf(h, w2b[ni], p1);
                    }
                    p0s[mi][r] = p0; p1s[mi][r] = p1;
                }
#pragma unroll
            for (int mi = 0; mi < 4; ++mi)
#pragma unroll
                for (int r = 0; r < 4; ++r) {
                    p0s[mi][r] += __shfl_xor(p0s[mi][r], 1);
                    p0s[mi][r] += __shfl_xor(p0s[mi][r], 2);
                    p1s[mi][r] += __shfl_xor(p1s[mi][r], 1);
                    p1s[mi][r] += __shfl_xor(p1s[mi][r], 2);
                }
            if ((lane & 3) == 0) {
                const int cw = wc * 4 + (l15 >> 2);
#pragma unroll
                for (int mi = 0; mi < 4; ++mi)
#pragma unroll
                    for (int r = 0; r < 4; ++r) {
                        const int row = wr * 64 + mi * 16 + l16 * 4 + r;   // 0..127
                        *(float2*)(lds + EPI_OFF + (row * 8 + (cw ^ (row & 7))) * 8)
                            = (float2){p0s[mi][r], p1s[mi][r]};
                    }
            }
            asm volatile("s_waitcnt lgkmcnt(0)" ::: "memory");
            __builtin_amdgcn_s_barrier();
            SB0();
            {
                const int row  = tid >> 1;     // 0..127, all 256 threads work
                const int half = tid & 1;
                float a0 = 0.f, b0 = 0.f;
#pragma unroll
                for (int q = 0; q < 4; ++q) {
                    const int cw = half * 4 + q;
                    const float2 v = *(const float2*)(lds + EPI_OFF
                                        + (row * 8 + (cw ^ (row & 7))) * 8);
                    a0 += v.x; b0 += v.y;
                }
                a0 += __shfl_xor(a0, 1);
                b0 += __shfl_xor(b0, 1);
                if (half == 0) {
                    const float alpha = a0 + b2[(size_t)s * 2 + 0];
                    const float beta  = b0 + b2[(size_t)s * 2 + 1];
                    const int grow = brow0 + row;
                    const float phi = z[(size_t)grow * D_DIM + idx];
                    const float u = tanf(0.5f * (phi - PI_F));
                    const float a = expf(alpha);
                    const float v = fmaf(a, u, beta);
                    x_out[(size_t)grow * D_DIM + idx] = 2.0f * atanf(v) + PI_F;
                    ld_acc += alpha + log1pf(u * u) - log1pf(v * v);
                }
            }
            __builtin_amdgcn_s_barrier();     // epi region reusable next site
        }
        if ((tid & 1) == 0) atomicAdd(ld_out + brow0 + (tid >> 1), ld_acc);
        if (c == 0 && tid < 128)
            x_out[(size_t)(brow0 + tid) * D_DIM] = z[(size_t)(brow0 + tid) * D_DIM];
        return;
#undef BODY
#undef ISSUE_A
#undef ISSUE_B
#undef ADV
    }

    // ---------------- legacy fallback: one site per block, in-kernel cvt ----
    const int wr2 = wid >> 1, wc2 = wid & 1;
    const int EPI2 = 32768;
    const int ib    = blockIdx.x;
    const int s_idx = ((ib >> 6) << 3) | (ib & 7);
    if (s_idx >= S_DIM) return;
    const int s     = S_DIM - 1 - s_idx;
    const int bblk  = (ib >> 3) & 7;
    const int brow0 = bblk * 128;
    const int K     = s + 1;
    const int idx   = s + 1;
    const float* __restrict__ W1s = W1 + (size_t)s * (D_DIM * H_DIM);

    f32x4 acc[4][4];
#pragma unroll
    for (int mi = 0; mi < 4; ++mi)
#pragma unroll
        for (int ni = 0; ni < 4; ++ni)
            acc[mi][ni] = (f32x4){0.f, 0.f, 0.f, 0.f};

    const int ntiles = (K + 63) >> 6;
    for (int kk = 0; kk < ntiles; ++kk) {
        const int k0 = kk << 6;
        const int g  = tid & 7;
        const int rb = tid >> 3;
#pragma unroll
        for (int p = 0; p < 4; ++p) {
            const int row  = p * 32 + rb;
            const int srcg = g ^ (row & 7);
            const float* zp = z + (size_t)(brow0 + row) * D_DIM + k0 + srcg * 8;
            float4 va = *(const float4*)zp;
            float4 vb = *(const float4*)(zp + 4);
            uint4 w;
            w.x = cvt_pk_bf16(va.x, va.y);
            w.y = cvt_pk_bf16(va.z, va.w);
            w.z = cvt_pk_bf16(vb.x, vb.y);
            w.w = cvt_pk_bf16(vb.z, vb.w);
            *(uint4*)(lds + row * 128 + g * 16) = w;
        }
        const int hgrp  = tid & 31;
        const int kgrp  = tid >> 5;
        const int kbase = k0 + kgrp * 8;
        const float* wp = W1s + (size_t)kbase * H_DIM + hgrp * 4;
        float4 cc[8];
#pragma unroll
        for (int jj = 0; jj < 8; ++jj) {
            float4 v = *(const float4*)(wp + (size_t)jj * H_DIM);
            const bool ok = (kbase + jj) < K;
            v.x = ok ? v.x : 0.f;  v.y = ok ? v.y : 0.f;
            v.z = ok ? v.z : 0.f;  v.w = ok ? v.w : 0.f;
            cc[jj] = v;
        }
        const float* cf = (const float*)cc;
#pragma unroll
        for (int i2 = 0; i2 < 4; ++i2) {
            const int h = hgrp * 4 + i2;
            uint4 w;
            w.x = cvt_pk_bf16(cf[0 * 4 + i2], cf[1 * 4 + i2]);
            w.y = cvt_pk_bf16(cf[2 * 4 + i2], cf[3 * 4 + i2]);
            w.z = cvt_pk_bf16(cf[4 * 4 + i2], cf[5 * 4 + i2]);
            w.w = cvt_pk_bf16(cf[6 * 4 + i2], cf[7 * 4 + i2]);
            *(uint4*)(lds + 16384 + h * 128 + ((kgrp * 16) ^ ((h & 7) << 4))) = w;
        }
        __syncthreads();
#pragma unroll
        for (int ks = 0; ks < 2; ++ks) {
            const int kb = ks * 64 + l16 * 16;
            short8 af[4], bfr[4];
#pragma unroll
            for (int mi = 0; mi < 4; ++mi) {
                const int r = wr2 * 64 + mi * 16 + l15;
                af[mi] = *(const short8*)(lds + r * 128 + (kb ^ ((r & 7) << 4)));
            }
#pragma unroll
            for (int ni = 0; ni < 4; ++ni) {
                const int h = wc2 * 64 + ni * 16 + l15;
                bfr[ni] = *(const short8*)(lds + 16384 + h * 128 + (kb ^ ((h & 7) << 4)));
            }
#pragma unroll
            for (int mi = 0; mi < 4; ++mi)
#pragma unroll
                for (int ni = 0; ni < 4; ++ni)
                    acc[mi][ni] = __builtin_amdgcn_mfma_f32_16x16x32_bf16(
                        af[mi], bfr[ni], acc[mi][ni], 0, 0, 0);
        }
        __syncthreads();
    }

    float b1v[4], w2a[4], w2b[4];
#pragma unroll
    for (int ni = 0; ni < 4; ++ni) {
        const int cc2 = wc2 * 64 + ni * 16 + l15;
        b1v[ni] = b1[(size_t)s * H_DIM + cc2];
        const float* w2p = W2 + ((size_t)s * H_DIM + cc2) * 2;
        w2a[ni] = w2p[0];
        w2b[ni] = w2p[1];
    }
    float p0s[4][4], p1s[4][4];
#pragma unroll
    for (int mi = 0; mi < 4; ++mi)
#pragma unroll
        for (int r = 0; r < 4; ++r) {
            float p0 = 0.f, p1 = 0.f;
#pragma unroll
            for (int ni = 0; ni < 4; ++ni) {
                float h = fmaxf(acc[mi][ni][r] + b1v[ni], 0.f);
                p0 = fmaf(h, w2a[ni], p0);
                p1 = fmaf(h, w2b[ni], p1);
            }
            p0s[mi][r] = p0; p1s[mi][r] = p1;
        }
#pragma unroll
    for (int mi = 0; mi < 4; ++mi)
#pragma unroll
        for (int r = 0; r < 4; ++r) {
            p0s[mi][r] += __shfl_xor(p0s[mi][r], 1);
            p0s[mi][r] += __shfl_xor(p0s[mi][r], 2);
            p1s[mi][r] += __shfl_xor(p1s[mi][r], 1);
            p1s[mi][r] += __shfl_xor(p1s[mi][r], 2);
        }
    if ((lane & 3) == 0) {
        const int cw = wc2 * 4 + (l15 >> 2);
#pragma unroll
        for (int mi = 0; mi < 4; ++mi)
#pragma unroll
            for (int r = 0; r < 4; ++r) {
                const int row = wr2 * 64 + mi * 16 + l16 * 4 + r;
                *(float2*)(lds + EPI2 + (row * 8 + (cw ^ (row & 7))) * 8)
                    = (float2){p0s[mi][r], p1s[mi][r]};
            }
    }
    __syncthreads();
    if (tid < 128) {
        const int row = tid;
        float alpha = b2[(size_t)s * 2 + 0];
        float beta  = b2[(size_t)s * 2 + 1];
#pragma unroll
        for (int cw = 0; cw < 8; ++cw) {
            const float2 v = *(const float2*)(lds + EPI2 + (row * 8 + (cw ^ (row & 7))) * 8);
            alpha += v.x; beta += v.y;
        }
        const int grow = brow0 + row;
        const float phi = z[(size_t)grow * D_DIM + idx];
        const float u = tanf(0.5f * (phi - PI_F));
        const float a = expf(alpha);
        const float v = fmaf(a, u, beta);
        x_out[(size_t)grow * D_DIM + idx] = 2.0f * atanf(v) + PI_F;
        atomicAdd(ld_out + grow, alpha + log1pf(u * u) - log1pf(v * v));
        if (s_idx == 0)
            x_out[(size_t)grow * D_DIM] = z[(size_t)grow * D_DIM];
    }
}

extern "C" void kernel_launch(void* const* d_in, const int* in_sizes, int n_in,
                              void* d_out, int out_size, void* d_ws, size_t ws_size,
                              hipStream_t stream) {
    const float* z  = (const float*)d_in[0];
    const float* W1 = (const float*)d_in[1];
    const float* b1 = (const float*)d_in[2];
    const float* W2 = (const float*)d_in[3];
    const float* b2 = (const float*)d_in[4];
    float* x_out  = (float*)d_out;
    float* ld_out = x_out + (size_t)B_DIM * D_DIM;

    unsigned char* z_frag = (unsigned char*)d_ws;
    unsigned char* w1bf   = z_frag + ZSWZ_BYTES;
    const size_t need = ZSWZ_BYTES + W1BF_BYTES;

    hipMemsetAsync(ld_out, 0, B_DIM * sizeof(float), stream);
    if (ws_size >= need) {
        pack_kernel<<<dim3(256 + 4088), dim3(256), 0, stream>>>(z, W1, z_frag, w1bf);
        ar_site_kernel<true><<<dim3(1024), dim3(256), 0, stream>>>(
            z, z_frag, w1bf, W1, b1, W2, b2, x_out, ld_out);
    } else {
        ar_site_kernel<false><<<dim3(4096), dim3(256), 0, stream>>>(
            z, nullptr, nullptr, W1, b1, W2, b2, x_out, ld_out);
    }
}

// Round 16
// 97.437 us; speedup vs baseline: 6.1579x; 1.1560x over previous
//
#include <hip/hip_runtime.h>
#include <math.h>

#define B_DIM 1024
#define D_DIM 512
#define H_DIM 128
#define S_DIM 511
#define PI_F 3.14159265358979323846f
#define ZSWZ_BYTES (8u * 1024u * 128u)      /* 1 MiB: z bf16, swizzle-baked */
#define CH_STRIDE 36                         /* max K-steps per chain (verified 32..36) */
#define W1BF_BYTES ((size_t)64 * CH_STRIDE * 16384)  /* 37.75 MiB chain-contiguous */
#define EPI_OFF 65536

typedef __attribute__((ext_vector_type(8))) short short8;
typedef __attribute__((ext_vector_type(4))) float f32x4;

#define GLDS16(src, dst)                                                        \
    __builtin_amdgcn_global_load_lds(                                           \
        (const __attribute__((address_space(1))) unsigned int*)(src),           \
        (__attribute__((address_space(3))) unsigned int*)(dst), 16, 0, 0)

static __device__ __forceinline__ unsigned cvt_pk_bf16(float lo, float hi) {
    unsigned r;
    asm("v_cvt_pk_bf16_f32 %0, %1, %2" : "=v"(r) : "v"(lo), "v"(hi));
    return r;
}

// snake site for (chain c, slot t): j index into descending-K order
static __device__ __forceinline__ int snake_j(int t, int c) {
    return t * 64 + ((t & 1) ? (63 - c) : c);
}

// ---------------------------------------------------------------------------
// Pack kernel. Blocks [0,256): z f32 -> bf16 swizzled tiles (R8 layout):
//   z_swz[kt][row][g*16] holds cols kt*64 + (g^(row&7))*8 ..+8
// Blocks [256, 256+64*36): W1 -> bf16 [h][k] swizzled 16KB tiles, laid out
//   CHAIN-CONTIGUOUS: w1bf[c][step] (step walks the chain's (site,kk) stream).
// ---------------------------------------------------------------------------
__global__ __launch_bounds__(256) void pack_kernel(
        const float* __restrict__ z, const float* __restrict__ W1,
        unsigned char* __restrict__ z_swz, unsigned char* __restrict__ w1bf)
{
    if (blockIdx.x < 256) {
        const int gid = blockIdx.x * 256 + threadIdx.x;   // 65536 threads
        const int g   = gid & 7;
        const int row = (gid >> 3) & 1023;
        const int kt  = gid >> 13;
        const int srcg = g ^ (row & 7);
        const float* src = z + (size_t)row * D_DIM + kt * 64 + srcg * 8;
        float4 a = *(const float4*)src;
        float4 b = *(const float4*)(src + 4);
        uint4 w;
        w.x = cvt_pk_bf16(a.x, a.y);
        w.y = cvt_pk_bf16(a.z, a.w);
        w.z = cvt_pk_bf16(b.x, b.y);
        w.w = cvt_pk_bf16(b.z, b.w);
        *(uint4*)(z_swz + (size_t)kt * 131072 + row * 128 + g * 16) = w;
        return;
    }
    const int idx  = blockIdx.x - 256;        // 0..2303
    const int c    = idx / CH_STRIDE;         // chain 0..63
    const int step = idx % CH_STRIDE;
    // map (c, step) -> (s, kk)
    int s = -1, kk = -1, acc = 0;
    for (int t = 0; t < 8; ++t) {
        const int j = snake_j(t, c);
        if (j >= S_DIM) continue;
        const int ss = 510 - j;
        const int nt = (ss >> 6) + 1;
        if (step < acc + nt) { s = ss; kk = step - acc; break; }
        acc += nt;
    }
    if (s < 0) return;                        // padding steps (csteps < 36)
    const int k0 = kk << 6;
    const int t  = threadIdx.x;
    const int h2 = t & 63;
    const int mw = t >> 6;
    const float* __restrict__ W1s = W1 + (size_t)s * (D_DIM * H_DIM);
    unsigned char* out = w1bf + ((size_t)c * CH_STRIDE + step) * 16384;
    const int h0 = h2 * 2, h1 = h2 * 2 + 1;
#pragma unroll
    for (int half = 0; half < 2; ++half) {
        const int m = mw + half * 4;
        float2 v[8];
#pragma unroll
        for (int e = 0; e < 8; ++e) {
            const int gk = k0 + m * 8 + e;
            v[e] = (gk <= s) ? *(const float2*)(W1s + (size_t)gk * H_DIM + h0)
                             : (float2){0.f, 0.f};
        }
        uint4 w0, w1;
        w0.x = cvt_pk_bf16(v[0].x, v[1].x); w0.y = cvt_pk_bf16(v[2].x, v[3].x);
        w0.z = cvt_pk_bf16(v[4].x, v[5].x); w0.w = cvt_pk_bf16(v[6].x, v[7].x);
        w1.x = cvt_pk_bf16(v[0].y, v[1].y); w1.y = cvt_pk_bf16(v[2].y, v[3].y);
        w1.z = cvt_pk_bf16(v[4].y, v[5].y); w1.w = cvt_pk_bf16(v[6].y, v[7].y);
        *(uint4*)(out + h0 * 128 + ((m ^ (h0 & 7)) << 4)) = w0;
        *(uint4*)(out + h1 * 128 + ((m ^ (h1 & 7)) << 4)) = w1;
    }
}

// ---------------------------------------------------------------------------
// Chained site kernel (R8 structure, chain-contiguous B): 512 blocks =
// 64 chains x 8 bblocks, 2 blocks/CU (72KB LDS). BK=64, 2-slot ring,
// depth-1 prefetch issued at TOP of body (full-step flight), one
// vmcnt(0)+barrier per step. B prefetch address is LINEAR (pf_step*16KB);
// only the cheap A-cursor (kk/nt per site) remains.
// ---------------------------------------------------------------------------
template<bool PRE>
__global__ __launch_bounds__(256, 2) void ar_site_kernel(
        const float* __restrict__ z, const unsigned char* __restrict__ z_swz,
        const unsigned char* __restrict__ w1bf,
        const float* __restrict__ W1, const float* __restrict__ b1,
        const float* __restrict__ W2, const float* __restrict__ b2,
        float* __restrict__ x_out, float* __restrict__ ld_out)
{
    __shared__ __align__(16) unsigned char lds[73728]; // ring 2x32KB + epi 8KB

    const int tid  = threadIdx.x;
    const int lane = tid & 63;
    const int wid  = tid >> 6;
    const int wr   = wid >> 1;
    const int wc   = wid & 1;
    const int l15  = lane & 15;
    const int l16  = lane >> 4;

    if (PRE) {
        const int ib   = blockIdx.x;            // 0..511
        const int c    = (((ib >> 3) & 7) << 3) | (ib & 7);  // chain 0..63
        const int bblk = ib >> 6;               // 0..7
        const int brow0 = bblk * 128;
        const unsigned char* __restrict__ w1chain =
            w1bf + (size_t)c * CH_STRIDE * 16384;

        // prefetch cursors: B = linear pf_step; A = (pf_kk within site pf_t)
        int pf_t = 0, pf_kk = 0, pf_step = 0;
        int pf_s = 510 - c;

        auto pf_stage = [&]() {
            if (pf_t >= 8) return;
            const int slot = pf_step & 1;
            const unsigned char* srcA = z_swz + (size_t)pf_kk * 131072
                                        + (size_t)brow0 * 128 + wid * 4096 + lane * 16;
            const unsigned char* srcB = w1chain + (size_t)pf_step * 16384
                                        + wid * 4096 + lane * 16;
            unsigned char* dstA = lds + slot * 32768 + wid * 4096;
            unsigned char* dstB = lds + slot * 32768 + 16384 + wid * 4096;
#pragma unroll
            for (int i2 = 0; i2 < 4; ++i2) {
                GLDS16(srcA + i2 * 1024, dstA + i2 * 1024);
                GLDS16(srcB + i2 * 1024, dstB + i2 * 1024);
            }
            ++pf_step; ++pf_kk;
            if (pf_kk == ((pf_s >> 6) + 1)) {
                pf_kk = 0; ++pf_t;
                while (pf_t < 8) {
                    const int j = snake_j(pf_t, c);
                    if (j < S_DIM) { pf_s = 510 - j; break; }
                    ++pf_t;
                }
            }
        };

        pf_stage();                    // depth-1 prologue: step 0 -> slot 0

        int step = 0;
        float ld_acc = 0.f;

        for (int t = 0; t < 8; ++t) {
            const int j = snake_j(t, c);
            if (j >= S_DIM) continue;
            const int s   = 510 - j;
            const int nt  = (s >> 6) + 1;
            const int idx = s + 1;

            f32x4 acc[4][4];
#pragma unroll
            for (int mi = 0; mi < 4; ++mi)
#pragma unroll
                for (int ni = 0; ni < 4; ++ni)
                    acc[mi][ni] = (f32x4){0.f, 0.f, 0.f, 0.f};

            for (int kk = 0; kk < nt; ++kk) {
                // step k's loads (issued at top of body k-1) — short drain
                asm volatile("s_waitcnt vmcnt(0)" ::: "memory");
                __builtin_amdgcn_s_barrier();
                __builtin_amdgcn_sched_barrier(0);
                const unsigned char* bufp = lds + (step & 1) * 32768;

                pf_stage();                          // stage step k+1 EARLY

                short8 af0[4], bf0[4], af1[4], bf1[4];
                {
                    const int kb = l16 * 16;
#pragma unroll
                    for (int mi = 0; mi < 4; ++mi) {
                        const int r = wr * 64 + mi * 16 + l15;
                        af0[mi] = *(const short8*)(bufp + r * 128 + (kb ^ ((r & 7) << 4)));
                    }
#pragma unroll
                    for (int ni = 0; ni < 4; ++ni) {
                        const int h = wc * 64 + ni * 16 + l15;
                        bf0[ni] = *(const short8*)(bufp + 16384 + h * 128 + (kb ^ ((h & 7) << 4)));
                    }
                }
                __builtin_amdgcn_s_setprio(1);
#pragma unroll
                for (int mi = 0; mi < 4; ++mi)
#pragma unroll
                    for (int ni = 0; ni < 4; ++ni)
                        acc[mi][ni] = __builtin_amdgcn_mfma_f32_16x16x32_bf16(
                            af0[mi], bf0[ni], acc[mi][ni], 0, 0, 0);
                __builtin_amdgcn_s_setprio(0);

                {
                    const int kb = 64 + l16 * 16;
#pragma unroll
                    for (int mi = 0; mi < 4; ++mi) {
                        const int r = wr * 64 + mi * 16 + l15;
                        af1[mi] = *(const short8*)(bufp + r * 128 + (kb ^ ((r & 7) << 4)));
                    }
#pragma unroll
                    for (int ni = 0; ni < 4; ++ni) {
                        const int h = wc * 64 + ni * 16 + l15;
                        bf1[ni] = *(const short8*)(bufp + 16384 + h * 128 + (kb ^ ((h & 7) << 4)));
                    }
                }
                __builtin_amdgcn_s_setprio(1);
#pragma unroll
                for (int mi = 0; mi < 4; ++mi)
#pragma unroll
                    for (int ni = 0; ni < 4; ++ni)
                        acc[mi][ni] = __builtin_amdgcn_mfma_f32_16x16x32_bf16(
                            af1[mi], bf1[ni], acc[mi][ni], 0, 0, 0);
                __builtin_amdgcn_s_setprio(0);
                ++step;
            }

            // ---- site epilogue: p = relu(acc+b1) @ W2, then NCP transform
            float b1v[4], w2a[4], w2b[4];
#pragma unroll
            for (int ni = 0; ni < 4; ++ni) {
                const int cc = wc * 64 + ni * 16 + l15;
                b1v[ni] = b1[(size_t)s * H_DIM + cc];
                const float2 w2v = *(const float2*)(W2 + ((size_t)s * H_DIM + cc) * 2);
                w2a[ni] = w2v.x;
                w2b[ni] = w2v.y;
            }
            float p0s[4][4], p1s[4][4];
#pragma unroll
            for (int mi = 0; mi < 4; ++mi)
#pragma unroll
                for (int r = 0; r < 4; ++r) {
                    float p0 = 0.f, p1 = 0.f;
#pragma unroll
                    for (int ni = 0; ni < 4; ++ni) {
                        float h = fmaxf(acc[mi][ni][r] + b1v[ni], 0.f);
                        p0 = fmaf(h, w2a[ni], p0);
                        p1 = fmaf(h, w2b[ni], p1);
                    }
                    p0s[mi][r] = p0; p1s[mi][r] = p1;
                }
#pragma unroll
            for (int mi = 0; mi < 4; ++mi)
#pragma unroll
                for (int r = 0; r < 4; ++r) {
                    p0s[mi][r] += __shfl_xor(p0s[mi][r], 1);
                    p0s[mi][r] += __shfl_xor(p0s[mi][r], 2);
                    p1s[mi][r] += __shfl_xor(p1s[mi][r], 1);
                    p1s[mi][r] += __shfl_xor(p1s[mi][r], 2);
                }
            if ((lane & 3) == 0) {
                const int cw = wc * 4 + (l15 >> 2);
#pragma unroll
                for (int mi = 0; mi < 4; ++mi)
#pragma unroll
                    for (int r = 0; r < 4; ++r) {
                        const int row = wr * 64 + mi * 16 + l16 * 4 + r;
                        *(float2*)(lds + EPI_OFF + (row * 8 + (cw ^ (row & 7))) * 8)
                            = (float2){p0s[mi][r], p1s[mi][r]};
                    }
            }
            asm volatile("s_waitcnt lgkmcnt(0)" ::: "memory");
            __builtin_amdgcn_s_barrier();
            __builtin_amdgcn_sched_barrier(0);
            if (tid < 128) {
                const int row = tid;
                float alpha = b2[(size_t)s * 2 + 0];
                float beta  = b2[(size_t)s * 2 + 1];
#pragma unroll
                for (int cw = 0; cw < 8; ++cw) {
                    const float2 v = *(const float2*)(lds + EPI_OFF + (row * 8 + (cw ^ (row & 7))) * 8);
                    alpha += v.x; beta += v.y;
                }
                const int grow = brow0 + row;
                const float phi = z[(size_t)grow * D_DIM + idx];
                const float u = tanf(0.5f * (phi - PI_F));
                const float a = expf(alpha);
                const float v = fmaf(a, u, beta);
                x_out[(size_t)grow * D_DIM + idx] = 2.0f * atanf(v) + PI_F;
                ld_acc += alpha + log1pf(u * u) - log1pf(v * v);
            }
            __builtin_amdgcn_s_barrier();     // epi region reusable next site
        }
        if (tid < 128) atomicAdd(ld_out + brow0 + tid, ld_acc);
        if (c == 0 && tid < 128)
            x_out[(size_t)(brow0 + tid) * D_DIM] = z[(size_t)(brow0 + tid) * D_DIM];
        return;
    }

    // ---------------- legacy fallback: one site per block, in-kernel cvt ----
    const int EPI2 = 65536;
    const int ib    = blockIdx.x;
    const int s_idx = ((ib >> 6) << 3) | (ib & 7);
    if (s_idx >= S_DIM) return;
    const int s     = S_DIM - 1 - s_idx;
    const int bblk  = (ib >> 3) & 7;
    const int brow0 = bblk * 128;
    const int K     = s + 1;
    const int idx   = s + 1;
    const float* __restrict__ W1s = W1 + (size_t)s * (D_DIM * H_DIM);

    f32x4 acc[4][4];
#pragma unroll
    for (int mi = 0; mi < 4; ++mi)
#pragma unroll
        for (int ni = 0; ni < 4; ++ni)
            acc[mi][ni] = (f32x4){0.f, 0.f, 0.f, 0.f};

    const int ntiles = (K + 63) >> 6;
    for (int kk = 0; kk < ntiles; ++kk) {
        const int k0 = kk << 6;
        const int g  = tid & 7;
        const int rb = tid >> 3;
#pragma unroll
        for (int p = 0; p < 4; ++p) {
            const int row  = p * 32 + rb;
            const int srcg = g ^ (row & 7);
            const float* zp = z + (size_t)(brow0 + row) * D_DIM + k0 + srcg * 8;
            float4 va = *(const float4*)zp;
            float4 vb = *(const float4*)(zp + 4);
            uint4 w;
            w.x = cvt_pk_bf16(va.x, va.y);
            w.y = cvt_pk_bf16(va.z, va.w);
            w.z = cvt_pk_bf16(vb.x, vb.y);
            w.w = cvt_pk_bf16(vb.z, vb.w);
            *(uint4*)(lds + row * 128 + g * 16) = w;
        }
        const int hgrp  = tid & 31;
        const int kgrp  = tid >> 5;
        const int kbase = k0 + kgrp * 8;
        const float* wp = W1s + (size_t)kbase * H_DIM + hgrp * 4;
        float4 cc[8];
#pragma unroll
        for (int jj = 0; jj < 8; ++jj) {
            float4 v = *(const float4*)(wp + (size_t)jj * H_DIM);
            const bool ok = (kbase + jj) < K;
            v.x = ok ? v.x : 0.f;  v.y = ok ? v.y : 0.f;
            v.z = ok ? v.z : 0.f;  v.w = ok ? v.w : 0.f;
            cc[jj] = v;
        }
        const float* cf = (const float*)cc;
#pragma unroll
        for (int i2 = 0; i2 < 4; ++i2) {
            const int h = hgrp * 4 + i2;
            uint4 w;
            w.x = cvt_pk_bf16(cf[0 * 4 + i2], cf[1 * 4 + i2]);
            w.y = cvt_pk_bf16(cf[2 * 4 + i2], cf[3 * 4 + i2]);
            w.z = cvt_pk_bf16(cf[4 * 4 + i2], cf[5 * 4 + i2]);
            w.w = cvt_pk_bf16(cf[6 * 4 + i2], cf[7 * 4 + i2]);
            *(uint4*)(lds + 16384 + h * 128 + ((kgrp * 16) ^ ((h & 7) << 4))) = w;
        }
        __syncthreads();
#pragma unroll
        for (int ks = 0; ks < 2; ++ks) {
            const int kb = ks * 64 + l16 * 16;
            short8 af[4], bfr[4];
#pragma unroll
            for (int mi = 0; mi < 4; ++mi) {
                const int r = wr * 64 + mi * 16 + l15;
                af[mi] = *(const short8*)(lds + r * 128 + (kb ^ ((r & 7) << 4)));
            }
#pragma unroll
            for (int ni = 0; ni < 4; ++ni) {
                const int h = wc * 64 + ni * 16 + l15;
                bfr[ni] = *(const short8*)(lds + 16384 + h * 128 + (kb ^ ((h & 7) << 4)));
            }
#pragma unroll
            for (int mi = 0; mi < 4; ++mi)
#pragma unroll
                for (int ni = 0; ni < 4; ++ni)
                    acc[mi][ni] = __builtin_amdgcn_mfma_f32_16x16x32_bf16(
                        af[mi], bfr[ni], acc[mi][ni], 0, 0, 0);
        }
        __syncthreads();
    }

    float b1v[4], w2a[4], w2b[4];
#pragma unroll
    for (int ni = 0; ni < 4; ++ni) {
        const int cc2 = wc * 64 + ni * 16 + l15;
        b1v[ni] = b1[(size_t)s * H_DIM + cc2];
        const float* w2p = W2 + ((size_t)s * H_DIM + cc2) * 2;
        w2a[ni] = w2p[0];
        w2b[ni] = w2p[1];
    }
    float p0s[4][4], p1s[4][4];
#pragma unroll
    for (int mi = 0; mi < 4; ++mi)
#pragma unroll
        for (int r = 0; r < 4; ++r) {
            float p0 = 0.f, p1 = 0.f;
#pragma unroll
            for (int ni = 0; ni < 4; ++ni) {
                float h = fmaxf(acc[mi][ni][r] + b1v[ni], 0.f);
                p0 = fmaf(h, w2a[ni], p0);
                p1 = fmaf(h, w2b[ni], p1);
            }
            p0s[mi][r] = p0; p1s[mi][r] = p1;
        }
#pragma unroll
    for (int mi = 0; mi < 4; ++mi)
#pragma unroll
        for (int r = 0; r < 4; ++r) {
            p0s[mi][r] += __shfl_xor(p0s[mi][r], 1);
            p0s[mi][r] += __shfl_xor(p0s[mi][r], 2);
            p1s[mi][r] += __shfl_xor(p1s[mi][r], 1);
            p1s[mi][r] += __shfl_xor(p1s[mi][r], 2);
        }
    if ((lane & 3) == 0) {
        const int cw = wc * 4 + (l15 >> 2);
#pragma unroll
        for (int mi = 0; mi < 4; ++mi)
#pragma unroll
            for (int r = 0; r < 4; ++r) {
                const int row = wr * 64 + mi * 16 + l16 * 4 + r;
                *(float2*)(lds + EPI2 + (row * 8 + (cw ^ (row & 7))) * 8)
                    = (float2){p0s[mi][r], p1s[mi][r]};
            }
    }
    __syncthreads();
    if (tid < 128) {
        const int row = tid;
        float alpha = b2[(size_t)s * 2 + 0];
        float beta  = b2[(size_t)s * 2 + 1];
#pragma unroll
        for (int cw = 0; cw < 8; ++cw) {
            const float2 v = *(const float2*)(lds + EPI2 + (row * 8 + (cw ^ (row & 7))) * 8);
            alpha += v.x; beta += v.y;
        }
        const int grow = brow0 + row;
        const float phi = z[(size_t)grow * D_DIM + idx];
        const float u = tanf(0.5f * (phi - PI_F));
        const float a = expf(alpha);
        const float v = fmaf(a, u, beta);
        x_out[(size_t)grow * D_DIM + idx] = 2.0f * atanf(v) + PI_F;
        atomicAdd(ld_out + grow, alpha + log1pf(u * u) - log1pf(v * v));
        if (s_idx == 0)
            x_out[(size_t)grow * D_DIM] = z[(size_t)grow * D_DIM];
    }
}

extern "C" void kernel_launch(void* const* d_in, const int* in_sizes, int n_in,
                              void* d_out, int out_size, void* d_ws, size_t ws_size,
                              hipStream_t stream) {
    const float* z  = (const float*)d_in[0];
    const float* W1 = (const float*)d_in[1];
    const float* b1 = (const float*)d_in[2];
    const float* W2 = (const float*)d_in[3];
    const float* b2 = (const float*)d_in[4];
    float* x_out  = (float*)d_out;
    float* ld_out = x_out + (size_t)B_DIM * D_DIM;

    unsigned char* z_swz = (unsigned char*)d_ws;
    unsigned char* w1bf  = z_swz + ZSWZ_BYTES;
    const size_t need = ZSWZ_BYTES + W1BF_BYTES;

    hipMemsetAsync(ld_out, 0, B_DIM * sizeof(float), stream);
    if (ws_size >= need) {
        pack_kernel<<<dim3(256 + 64 * CH_STRIDE), dim3(256), 0, stream>>>(z, W1, z_swz, w1bf);
        ar_site_kernel<true><<<dim3(512), dim3(256), 0, stream>>>(
            z, z_swz, w1bf, W1, b1, W2, b2, x_out, ld_out);
    } else {
        ar_site_kernel<false><<<dim3(4096), dim3(256), 0, stream>>>(
            z, nullptr, nullptr, W1, b1, W2, b2, x_out, ld_out);
    }
}